// Round 9
// baseline (1953.231 us; speedup 1.0000x reference)
//
#include <hip/hip_runtime.h>
#include <cmath>

#define BB 64
#define TT 2048
#define FF 64
#define HH 160
#define G3 480
#define TC 128            // time-chunk length
#define NC (TT / TC)      // 16 chunks

#define L2E  1.44269504088896340736f
#define TL2E 2.88539008177792681472f

typedef unsigned int u32;
typedef _Float16 half8 __attribute__((ext_vector_type(8)));
typedef _Float16 half2v __attribute__((ext_vector_type(2)));
typedef float f32x4 __attribute__((ext_vector_type(4)));

__device__ __forceinline__ unsigned short f2h(float v) {
    _Float16 h = (_Float16)v;
    return __builtin_bit_cast(unsigned short, h);
}
__device__ __forceinline__ u32 packh2(float a, float b) {
    return (u32)f2h(a) | ((u32)f2h(b) << 16);
}
__device__ __forceinline__ u32 packhh(_Float16 a, _Float16 b) {
    return (u32)__builtin_bit_cast(unsigned short, a)
         | ((u32)__builtin_bit_cast(unsigned short, b) << 16);
}
// select f16 half by precomputed shift (0 or 16), then convert
__device__ __forceinline__ float h2sel(u32 p, u32 sh) {
    return (float)__builtin_bit_cast(half2v, p >> sh)[0];
}
// fast 1-ulp reciprocal / exp2 (avoid IEEE div + libm: no fast-math in harness)
__device__ __forceinline__ float frcp(float v) { return __builtin_amdgcn_rcpf(v); }
#if __has_builtin(__builtin_amdgcn_exp2f)
__device__ __forceinline__ float fexp2(float v) { return __builtin_amdgcn_exp2f(v); }
#else
__device__ __forceinline__ float fexp2(float v) { return __expf(v * 0.69314718055994530942f); }
#endif
__device__ __forceinline__ float gelu_exact(float v) {
    return 0.5f * v * (1.f + erff(v * 0.70710678118654752f));
}
// barrier that waits only on LDS ops (NOT vmcnt)
__device__ __forceinline__ void barrier_lgkm() {
    asm volatile("s_waitcnt lgkmcnt(0)\ns_barrier" ::: "memory");
}
// extract C[dup] from f32x4 with static cndmask tree (no runtime array idx)
__device__ __forceinline__ float csel(f32x4 C, bool d1, bool d2) {
    float ca = d1 ? C[1] : C[0];
    float cb = d1 ? C[3] : C[2];
    return d2 ? cb : ca;
}
// scaled variant: w -> f16(w * s). Folds log2(e) into gate weights so the
// scan's sigmoid/tanh use raw v_exp_f32 (exp2) with no pre-multiply.
__device__ __forceinline__ half8 load_wrow8s(const float* p, float s) {
    const float4* q = (const float4*)p;
    float4 a = q[0], b = q[1];
    half8 r;
    r[0] = (_Float16)(a.x * s); r[1] = (_Float16)(a.y * s);
    r[2] = (_Float16)(a.z * s); r[3] = (_Float16)(a.w * s);
    r[4] = (_Float16)(b.x * s); r[5] = (_Float16)(b.y * s);
    r[6] = (_Float16)(b.z * s); r[7] = (_Float16)(b.w * s);
    return r;
}
// split f32x8 into hi(f16) + lo(f16 of residual): hi+lo reproduces f32 to ~2^-22
__device__ __forceinline__ void split8(const float* v, half8& hi, half8& lo) {
    #pragma unroll
    for (int j = 0; j < 8; ++j) {
        _Float16 h = (_Float16)v[j];
        hi[j] = h;
        lo[j] = (_Float16)(v[j] - (float)h);
    }
}
#define MM16(A_, B_, C_) __builtin_amdgcn_mfma_f32_16x16x32_f16(A_, B_, C_, 0, 0, 0)

// ---------------------------------------------------------------------------
// K1: dilated conv + BN + exact GELU via MFMA (split-f16 for f32 accuracy).
// 64-t tiles (19 KB LDS -> 8 blocks/CU). x staged into LDS once (coalesced,
// pre-split hi/lo); z stored via LDS transpose tile (coalesced stores).
// ---------------------------------------------------------------------------
__global__ __launch_bounds__(256) void conv_mfma_kernel(
    const float* __restrict__ x, const float* __restrict__ mix_w,
    const float* __restrict__ bn_g, const float* __restrict__ bn_b,
    const float* __restrict__ bn_m, const float* __restrict__ bn_v,
    u32* __restrict__ z_out)
{
    __shared__ __align__(16) u32 xs[68 * 68];
    __shared__ __align__(8)  u32 zt[16 * 34];

    const int b   = blockIdx.y;
    const int t0  = blockIdx.x * 64;
    const int tid = threadIdx.x;
    const int wv = tid >> 6;
    const int lane = tid & 63;
    const int lane15 = lane & 15;
    const int quad = lane >> 4;

    {
        const float* xb = x + (size_t)b * TT * FF;
        for (int idx = tid; idx < 68 * 32; idx += 256) {
            const int row = idx >> 5;
            const int fp  = (idx & 31) * 2;
            const int t = t0 - 2 + row;
            float v0 = 0.f, v1 = 0.f;
            if (t >= 0 && t < TT) {
                float2 v = *(const float2*)(xb + (size_t)t * FF + fp);
                v0 = v.x; v1 = v.y;
            }
            _Float16 h0 = (_Float16)v0, h1 = (_Float16)v1;
            _Float16 l0 = (_Float16)(v0 - (float)h0);
            _Float16 l1 = (_Float16)(v1 - (float)h1);
            u32* rw = xs + row * 68;
            rw[(fp >> 1)]      = packhh(h0, h1);
            rw[32 + (fp >> 1)] = packhh(l0, l1);
        }
    }

    half8 Ahi[6], Alo[6];
    {
        const int fo = wv * 16 + lane15;
        const float* wrow = mix_w + fo * 192;
        #pragma unroll
        for (int s = 0; s < 6; ++s) {
            float wf[8];
            #pragma unroll
            for (int j = 0; j < 8; ++j) {
                int kap = s * 32 + quad * 8 + j;
                wf[j] = wrow[(kap & 63) * 3 + (kap >> 6)];
            }
            split8(wf, Ahi[s], Alo[s]);
        }
    }
    float sc[4], sh[4];
    #pragma unroll
    for (int r = 0; r < 4; ++r) {
        int f = wv * 16 + quad * 4 + r;
        float scl = bn_g[f] * rsqrtf(bn_v[f] + 1e-5f);
        sc[r] = scl; sh[r] = bn_b[f] - bn_m[f] * scl;
    }

    __syncthreads();

    u32* zrow = z_out + (size_t)(b >> 4) * TT * 512 + (b & 15) * 32;
    const int srow = tid >> 4;
    const int sc2  = tid & 15;

    for (int tt = 0; tt < 4; ++tt) {
        f32x4 C = {0.f, 0.f, 0.f, 0.f};
        #pragma unroll
        for (int s = 0; s < 6; ++s) {
            const int row = tt * 16 + lane15 + 2 * (s >> 1);
            const u32* rp = xs + row * 68 + (s & 1) * 16 + quad * 4;
            half8 Bhi = __builtin_bit_cast(half8, *(const uint4*)(rp));
            half8 Blo = __builtin_bit_cast(half8, *(const uint4*)(rp + 32));
            C = MM16(Ahi[s], Bhi, C);
            C = MM16(Ahi[s], Blo, C);
            C = MM16(Alo[s], Bhi, C);
        }
        float z0 = gelu_exact(fmaf(C[0], sc[0], sh[0]));
        float z1 = gelu_exact(fmaf(C[1], sc[1], sh[1]));
        float z2 = gelu_exact(fmaf(C[2], sc[2], sh[2]));
        float z3 = gelu_exact(fmaf(C[3], sc[3], sh[3]));
        const u32 q0 = packh2(z0, z1);
        const u32 q1 = packh2(z2, z3);
        __syncthreads();
        *(uint2*)(zt + lane15 * 34 + wv * 8 + quad * 2) = (uint2){q0, q1};
        __syncthreads();
        uint2 v = *(const uint2*)(zt + srow * 34 + sc2 * 2);
        *(uint2*)(zrow + (size_t)(t0 + tt * 16 + srow) * 512 + sc2 * 2) = v;
    }
}

// ---------------------------------------------------------------------------
// GEMM device body (MFMA): xg[t][tile][chain][n'/2] f16 pairs. 512 workers.
// Weights/biases pre-scaled by L2E (r,z: tiles 0..19) / TL2E (n: 20..29).
// ---------------------------------------------------------------------------
#define DECLAI(i) half8 A##i##_0, A##i##_1, A##i##_2, A##i##_3, A##i##_4;
#define GLOADA(i) { int tl = wv4 + (i); int rowc = tl < 30 ? tl * 16 + lane15 : 479; \
    float sA = tl < 20 ? L2E : TL2E;                                                 \
    const float* wp = W + (size_t)rowc * K + quad * 8;                               \
    A##i##_0 = load_wrow8s(wp, sA); A##i##_1 = load_wrow8s(wp + 32, sA);             \
    if (KT > 2) { A##i##_2 = load_wrow8s(wp + 64, sA);                               \
                  A##i##_3 = load_wrow8s(wp + 96, sA);                               \
                  A##i##_4 = load_wrow8s(wp + 128, sA); }                            \
    else { A##i##_2 = A##i##_0; A##i##_3 = A##i##_0; A##i##_4 = A##i##_0; } }
#define GMM(i, kt) C##i = MM16(A##i##_##kt, Bk##kt, C##i);

template<int K, int KT, int TG>
__device__ __forceinline__ void gemm_body(
    const unsigned short* __restrict__ in,
    size_t in_blk_stride, int t_off,
    const float* __restrict__ W, const float* __restrict__ b_ih,
    const float* __restrict__ b_hh, u32* __restrict__ xg,
    int gidx, int tid)
{
    if (tid >= 512) return;
    const int wv4 = (tid >> 6) * 4;
    const int lane = tid & 63;
    const int lane15 = lane & 15;
    const int quad = lane >> 4;
    const int blk = gidx >> 4;
    const int tbase = (gidx & 15) * TG;

    DECLAI(0) DECLAI(1) DECLAI(2) DECLAI(3)
    GLOADA(0) GLOADA(1) GLOADA(2) GLOADA(3)

    f32x4 BIAS0, BIAS1, BIAS2, BIAS3;
    #define GBIAS(i) { int tl = wv4 + (i); int rowb = tl < 30 ? tl * 16 + quad * 4 : 476; \
        float sB = tl < 20 ? L2E : TL2E;                                                  \
        float4 bi = *(const float4*)(b_ih + rowb);                                        \
        if (tl < 20) { float4 bh = *(const float4*)(b_hh + rowb);                         \
            bi.x += bh.x; bi.y += bh.y; bi.z += bh.z; bi.w += bh.w; }                     \
        BIAS##i[0] = bi.x * sB; BIAS##i[1] = bi.y * sB;                                   \
        BIAS##i[2] = bi.z * sB; BIAS##i[3] = bi.w * sB; }
    GBIAS(0) GBIAS(1) GBIAS(2) GBIAS(3)
    #undef GBIAS

    const unsigned short* inb = in + (size_t)blk * in_blk_stride;
    u32* xgb = xg + (size_t)blk * TC * 3840;

    for (int t = 0; t < TG; ++t) {
        const int tt = tbase + t;
        const unsigned short* ip =
            inb + ((size_t)(t_off + tt) * 16 + lane15) * K + quad * 8;
        half8 Bk0 = __builtin_bit_cast(half8, *(const uint4*)(ip));
        half8 Bk1 = __builtin_bit_cast(half8, *(const uint4*)(ip + 32));
        half8 Bk2 = Bk0, Bk3 = Bk0, Bk4 = Bk0;
        if (KT > 2) {
            Bk2 = __builtin_bit_cast(half8, *(const uint4*)(ip + 64));
            Bk3 = __builtin_bit_cast(half8, *(const uint4*)(ip + 96));
            Bk4 = __builtin_bit_cast(half8, *(const uint4*)(ip + 128));
        }
        f32x4 C0 = BIAS0, C1 = BIAS1, C2 = BIAS2, C3 = BIAS3;
        GMM(0, 0) GMM(1, 0) GMM(2, 0) GMM(3, 0)
        GMM(0, 1) GMM(1, 1) GMM(2, 1) GMM(3, 1)
        if (KT > 2) {
            GMM(0, 2) GMM(1, 2) GMM(2, 2) GMM(3, 2)
            GMM(0, 3) GMM(1, 3) GMM(2, 3) GMM(3, 3)
            GMM(0, 4) GMM(1, 4) GMM(2, 4) GMM(3, 4)
        }
        #define GSTORE(i) { int tl = wv4 + (i); if (tl < 30) {                      \
            u32 q0 = packh2(C##i[0], C##i[1]);                                      \
            u32 q1 = packh2(C##i[2], C##i[3]);                                      \
            *(uint2*)(xgb + (((size_t)tt * 30 + tl) * 16 + lane15) * 8 + quad * 2)  \
                = (uint2){q0, q1}; } }
        GSTORE(0) GSTORE(1) GSTORE(2) GSTORE(3)
        #undef GSTORE
    }
}

// ---------------------------------------------------------------------------
// Scan device body: *** 5 compute waves (tid<320), 4 chains, 32 rows/wave ***.
// Wave wv owns h-rows [32wv, 32wv+32) for all 3 gates: 6 MFMA chains
// (tiles 2wv,2wv+1 / 10+2wv,11+2wv / 20+2wv,21+2wv), reading h from LDS
// ONCE per step (5 ds_read_b128) -> 25 reads/CU/step (was 50 with 10 waves).
// Chains duplicated 4x across B-columns; dup=lane15>>2 picks the C row;
// each lane owns 2 rows (one per tile) = 2 gate triples.
// LDS chain stride 416 B (104 dwords == 8 mod 32): chain bank phases
// {0,8,16,24}, every bank exactly 2-way on b128 reads = conflict-free.
// Waves 5..7 spin matching barriers (1 syncthreads + TC barrier_lgkm).
// ---------------------------------------------------------------------------
#define DECLW(nm) half8 nm##0, nm##1, nm##2, nm##3, nm##4;
#define LOADWHS(nm, tb, S) { const float* wp = w_hh + (size_t)((tb) * 16 + lane15) * HH + quad * 8; \
    nm##0 = load_wrow8s(wp, S);       nm##1 = load_wrow8s(wp + 32, S);                              \
    nm##2 = load_wrow8s(wp + 64, S);  nm##3 = load_wrow8s(wp + 96, S);                              \
    nm##4 = load_wrow8s(wp + 128, S); }

template<bool WRITE_H>
__device__ __forceinline__ void scan_body(
    const u32* __restrict__ xg,          // f16 pairs [4][TC][30][16][8] u32
    const float* __restrict__ w_hh, const float* __restrict__ b_hh,
    float* __restrict__ h_state,         // [64][160] f32 carry
    u32* __restrict__ h_out32,           // [4][TC][16][160] f16 (if WRITE_H)
    int first, int blk, int sub, int tid, u32* h_lds32)
{
    if (tid >= 320) {                    // barrier-matching spin waves
        __syncthreads();
        for (int t = 0; t < TC; ++t) barrier_lgkm();
        return;
    }
    const int wv = tid >> 6;             // 0..4
    const int lane = tid & 63;
    const int lane15 = lane & 15;
    const int quad = lane >> 4;
    const int ch   = lane15 & 3;         // chain within the block's 4
    const int dup  = lane15 >> 2;        // C-row select (0..3)
    const int ch0  = sub * 4;            // global chain base within blk
    const int row0 = 32 * wv + quad * 4 + dup;   // T0 h-row this lane owns
    const int row1 = row0 + 16;                  // T1 h-row
    const u32 shamt = 16u * (u32)(dup & 1);
    const bool d1 = (dup & 1) != 0;
    const bool d2 = (dup & 2) != 0;

    DECLW(Ra) DECLW(Rb) DECLW(Za) DECLW(Zb) DECLW(Na) DECLW(Nb)
    LOADWHS(Ra, 2 * wv, L2E)      LOADWHS(Rb, 2 * wv + 1, L2E)
    LOADWHS(Za, 10 + 2 * wv, L2E) LOADWHS(Zb, 11 + 2 * wv, L2E)
    LOADWHS(Na, 20 + 2 * wv, TL2E) LOADWHS(Nb, 21 + 2 * wv, TL2E)

    const float bh0 = b_hh[320 + row0] * TL2E;
    const float bh1 = b_hh[320 + row1] * TL2E;

    float* hsp = h_state + (size_t)(blk * 16 + ch0 + ch) * HH;
    float ho0 = 0.f, ho1 = 0.f;
    if (!first) { ho0 = hsp[row0]; ho1 = hsp[row1]; }

    // LDS: per parity [chain 4][208 u16] (416 B stride); parity1 at +832 u16
    unsigned short* hb16 = (unsigned short*)h_lds32;
    unsigned short* W0 = hb16 + ch * 208;
    unsigned short* W1 = W0 + 832;
    W0[row0] = f2h(ho0);
    W0[row1] = f2h(ho1);

    // B-fragment read base (uint4 units): slice i at vb + 4i
    const int vb = ch * 26 + quad;

    const u32* xgb = xg + (size_t)blk * TC * 3840;
    const int pr = quad * 2 + (dup >> 1);
    const int xo = ((2 * wv) * 16 + ch0 + ch) * 8 + pr;   // tile 2wv base
    // offsets from xo: +128 (T1), +1280/+1408 (z), +2560/+2688 (n)

    // 4-deep prefetch ring: 6 u32 per step slot
    u32 r0A = xgb[0 * 3840 + xo],        r1A = xgb[0 * 3840 + xo + 128];
    u32 z0A = xgb[0 * 3840 + xo + 1280], z1A = xgb[0 * 3840 + xo + 1408];
    u32 n0A = xgb[0 * 3840 + xo + 2560], n1A = xgb[0 * 3840 + xo + 2688];
    u32 r0B = xgb[1 * 3840 + xo],        r1B = xgb[1 * 3840 + xo + 128];
    u32 z0B = xgb[1 * 3840 + xo + 1280], z1B = xgb[1 * 3840 + xo + 1408];
    u32 n0B = xgb[1 * 3840 + xo + 2560], n1B = xgb[1 * 3840 + xo + 2688];
    u32 r0C = xgb[2 * 3840 + xo],        r1C = xgb[2 * 3840 + xo + 128];
    u32 z0C = xgb[2 * 3840 + xo + 1280], z1C = xgb[2 * 3840 + xo + 1408];
    u32 n0C = xgb[2 * 3840 + xo + 2560], n1C = xgb[2 * 3840 + xo + 2688];
    u32 r0D = xgb[3 * 3840 + xo],        r1D = xgb[3 * 3840 + xo + 128];
    u32 z0D = xgb[3 * 3840 + xo + 1280], z1D = xgb[3 * 3840 + xo + 1408];
    u32 n0D = xgb[3 * 3840 + xo + 2560], n1D = xgb[3 * 3840 + xo + 2688];
    const u32* pf = xgb + 4 * 3840 + xo;   // t+4 prefetch base

    // h1c: f16 at [blk][t][chain 16][row 160]
    unsigned short* hp = WRITE_H
            ? (unsigned short*)h_out32 + (size_t)blk * TC * 2560
              + (size_t)(ch0 + ch) * 160 + row0
            : nullptr;
    __syncthreads();

    #define SCAN_STEP(RBOFF, WP, Xr0, Xr1, Xz0, Xz1, Xn0, Xn1, PFO, HPO)             \
    {                                                                                \
        const uint4* hb = (const uint4*)h_lds32 + (RBOFF);                           \
        uint4 hq0 = hb[vb];      uint4 hq1 = hb[vb + 4];                             \
        uint4 hq2 = hb[vb + 8];  uint4 hq3 = hb[vb + 12];                            \
        uint4 hq4 = hb[vb + 16];                                                     \
        float xr0v = h2sel(Xr0, shamt), xr1v = h2sel(Xr1, shamt);                    \
        float xz0v = h2sel(Xz0, shamt), xz1v = h2sel(Xz1, shamt);                    \
        float xn0v = h2sel(Xn0, shamt), xn1v = h2sel(Xn1, shamt);                    \
        f32x4 Cr0 = {xr0v, xr0v, xr0v, xr0v}, Cr1 = {xr1v, xr1v, xr1v, xr1v};        \
        f32x4 Cz0 = {xz0v, xz0v, xz0v, xz0v}, Cz1 = {xz1v, xz1v, xz1v, xz1v};        \
        f32x4 Cn0 = {bh0, bh0, bh0, bh0},     Cn1 = {bh1, bh1, bh1, bh1};            \
        Xr0 = pf[(PFO)];        Xr1 = pf[(PFO) + 128];                               \
        Xz0 = pf[(PFO) + 1280]; Xz1 = pf[(PFO) + 1408];                              \
        Xn0 = pf[(PFO) + 2560]; Xn1 = pf[(PFO) + 2688];                              \
        half8 Bx;                                                                    \
        Bx = __builtin_bit_cast(half8, hq0);                                         \
        Cr0 = MM16(Ra0, Bx, Cr0); Cr1 = MM16(Rb0, Bx, Cr1);                          \
        Cz0 = MM16(Za0, Bx, Cz0); Cz1 = MM16(Zb0, Bx, Cz1);                          \
        Cn0 = MM16(Na0, Bx, Cn0); Cn1 = MM16(Nb0, Bx, Cn1);                          \
        Bx = __builtin_bit_cast(half8, hq1);                                         \
        Cr0 = MM16(Ra1, Bx, Cr0); Cr1 = MM16(Rb1, Bx, Cr1);                          \
        Cz0 = MM16(Za1, Bx, Cz0); Cz1 = MM16(Zb1, Bx, Cz1);                          \
        Cn0 = MM16(Na1, Bx, Cn0); Cn1 = MM16(Nb1, Bx, Cn1);                          \
        Bx = __builtin_bit_cast(half8, hq2);                                         \
        Cr0 = MM16(Ra2, Bx, Cr0); Cr1 = MM16(Rb2, Bx, Cr1);                          \
        Cz0 = MM16(Za2, Bx, Cz0); Cz1 = MM16(Zb2, Bx, Cz1);                          \
        Cn0 = MM16(Na2, Bx, Cn0); Cn1 = MM16(Nb2, Bx, Cn1);                          \
        Bx = __builtin_bit_cast(half8, hq3);                                         \
        Cr0 = MM16(Ra3, Bx, Cr0); Cr1 = MM16(Rb3, Bx, Cr1);                          \
        Cz0 = MM16(Za3, Bx, Cz0); Cz1 = MM16(Zb3, Bx, Cz1);                          \
        Cn0 = MM16(Na3, Bx, Cn0); Cn1 = MM16(Nb3, Bx, Cn1);                          \
        Bx = __builtin_bit_cast(half8, hq4);                                         \
        Cr0 = MM16(Ra4, Bx, Cr0); Cr1 = MM16(Rb4, Bx, Cr1);                          \
        Cz0 = MM16(Za4, Bx, Cz0); Cz1 = MM16(Zb4, Bx, Cz1);                          \
        Cn0 = MM16(Na4, Bx, Cn0); Cn1 = MM16(Nb4, Bx, Cn1);                          \
        {                                                                            \
            float crv = csel(Cr0, d1, d2);                                           \
            float czv = csel(Cz0, d1, d2);                                           \
            float cnv = csel(Cn0, d1, d2);                                           \
            float r = frcp(1.f + fexp2(-crv));                                       \
            float u = frcp(1.f + fexp2(-czv));                                       \
            float e = fexp2(fmaf(r, cnv, xn0v));                                     \
            float n = fmaf(-2.f, frcp(e + 1.f), 1.f);                                \
            ho0 = fmaf(u, ho0 - n, n);                                               \
        }                                                                            \
        {                                                                            \
            float crv = csel(Cr1, d1, d2);                                           \
            float czv = csel(Cz1, d1, d2);                                           \
            float cnv = csel(Cn1, d1, d2);                                           \
            float r = frcp(1.f + fexp2(-crv));                                       \
            float u = frcp(1.f + fexp2(-czv));                                       \
            float e = fexp2(fmaf(r, cnv, xn1v));                                     \
            float n = fmaf(-2.f, frcp(e + 1.f), 1.f);                                \
            ho1 = fmaf(u, ho1 - n, n);                                               \
        }                                                                            \
        const unsigned short hv0 = f2h(ho0);                                         \
        const unsigned short hv1 = f2h(ho1);                                         \
        (WP)[row0] = hv0;                                                            \
        (WP)[row1] = hv1;                                                            \
        if (WRITE_H) { hp[(HPO)] = hv0; hp[(HPO) + 16] = hv1; }                      \
        barrier_lgkm();                                                              \
    }

    for (int t4 = 0; t4 < TC; t4 += 4) {
        SCAN_STEP(0,   W1, r0A, r1A, z0A, z1A, n0A, n1A, 0 * 3840, 0 * 2560)
        SCAN_STEP(104, W0, r0B, r1B, z0B, z1B, n0B, n1B, 1 * 3840, 1 * 2560)
        SCAN_STEP(0,   W1, r0C, r1C, z0C, z1C, n0C, n1C, 2 * 3840, 2 * 2560)
        SCAN_STEP(104, W0, r0D, r1D, z0D, z1D, n0D, n1D, 3 * 3840, 3 * 2560)
        pf += 4 * 3840;
        if (WRITE_H) hp += 4 * 2560;
    }
    #undef SCAN_STEP

    hsp[row0] = ho0;
    hsp[row1] = ho1;
}

// ---------------------------------------------------------------------------
// K2: pipelined mega-dispatch (512 threads: VGPR cap 256/wave so the 5-wave
// scan's ~200-VGPR working set fits; gemm always used 512 workers).
//   blocks 0..15   : scan1 chunk k-1   (blk = bx>>2, sub = bx&3)
//   blocks 16..31  : scan2 chunk k-3
//   blocks 32..95  : gemm1 chunk k     (64 blocks, TG=8)
//   blocks 96..159 : gemm2 chunk k-2   (64 blocks, TG=8)
// Producer->consumer edges cross dispatch boundaries; parity (chunk&1)
// double-buffers xg1/xg2/h1c. Scan prefetch over-reads <=4 steps; stays in ws.
// ---------------------------------------------------------------------------
__global__ __launch_bounds__(512, 1) void pipe_stage(
    const u32* __restrict__ z,           // [4][TT][16][32] u32
    u32* __restrict__ xg1,               // 2 x [4][TC][3840] u32
    u32* __restrict__ xg2,
    u32* __restrict__ h1c,               // 2 x [4][TC][1280] u32
    float* __restrict__ h1s, float* __restrict__ h2s,
    const float* __restrict__ w_ih1, const float* __restrict__ b_ih1,
    const float* __restrict__ w_hh1, const float* __restrict__ b_hh1,
    const float* __restrict__ w_ih2, const float* __restrict__ b_ih2,
    const float* __restrict__ w_hh2, const float* __restrict__ b_hh2,
    int k)
{
    __shared__ __align__(16) u32 h_lds32[2 * 416];
    const int bx = blockIdx.x;
    const int tid = threadIdx.x;
    const size_t XGCH = (size_t)4 * TC * 3840;   // u32 per parity buffer
    const size_t H1CH = (size_t)4 * TC * 1280;

    if (bx < 16) {
        const int c = k - 1;
        if (c < 0 || c >= NC) return;
        scan_body<true>(xg1 + (c & 1) * XGCH, w_hh1, b_hh1, h1s,
                        h1c + (c & 1) * H1CH, c == 0, bx >> 2, bx & 3, tid, h_lds32);
    } else if (bx < 32) {
        const int c = k - 3;
        if (c < 0 || c >= NC) return;
        scan_body<false>(xg2 + (c & 1) * XGCH, w_hh2, b_hh2, h2s,
                         nullptr, c == 0, (bx - 16) >> 2, (bx - 16) & 3, tid, h_lds32);
    } else if (bx < 96) {
        const int c = k;
        if (c >= NC) return;
        gemm_body<64, 2, 8>((const unsigned short*)z, (size_t)TT * 1024, c * TC,
                            w_ih1, b_ih1, b_hh1, xg1 + (c & 1) * XGCH, bx - 32, tid);
    } else {
        const int c = k - 2;
        if (c < 0 || c >= NC) return;
        gemm_body<160, 5, 8>((const unsigned short*)(h1c + (c & 1) * H1CH),
                             (size_t)TC * 2560, 0,
                             w_ih2, b_ih2, b_hh2, xg2 + (c & 1) * XGCH, bx - 96, tid);
    }
}

// ---------------------------------------------------------------------------
// K3: MLP head from h2 final state.
// ---------------------------------------------------------------------------
__global__ __launch_bounds__(256) void head_kernel(
    const float* __restrict__ h_state,
    const float* __restrict__ hw1, const float* __restrict__ hb1,
    const float* __restrict__ hw2, const float* __restrict__ hb2,
    float* __restrict__ out)
{
    const int b = blockIdx.x;
    const int tid = threadIdx.x;
    __shared__ float hf[HH];
    __shared__ float q[80];
    if (tid < HH) hf[tid] = h_state[b * HH + tid];
    __syncthreads();
    if (tid < 80) {
        float a = hb1[tid];
        const float* wr = hw1 + (size_t)tid * HH;
        #pragma unroll 8
        for (int i = 0; i < HH; ++i) a = fmaf(wr[i], hf[i], a);
        q[tid] = gelu_exact(a);
    }
    __syncthreads();
    if (tid < 2) {
        float o = hb2[tid];
        const float* wr = hw2 + tid * 80;
        #pragma unroll 8
        for (int j = 0; j < 80; ++j) o = fmaf(wr[j], q[j], o);
        out[b * 2 + tid] = o;
    }
}

// ---------------------------------------------------------------------------
extern "C" void kernel_launch(void* const* d_in, const int* in_sizes, int n_in,
                              void* d_out, int out_size, void* d_ws, size_t ws_size,
                              hipStream_t stream)
{
    const float* x     = (const float*)d_in[0];
    const float* mix_w = (const float*)d_in[1];
    const float* bn_g  = (const float*)d_in[2];
    const float* bn_b  = (const float*)d_in[3];
    const float* bn_m  = (const float*)d_in[4];
    const float* bn_v  = (const float*)d_in[5];
    const float* w_ih1 = (const float*)d_in[6];
    const float* w_hh1 = (const float*)d_in[7];
    const float* b_ih1 = (const float*)d_in[8];
    const float* b_hh1 = (const float*)d_in[9];
    const float* w_ih2 = (const float*)d_in[10];
    const float* w_hh2 = (const float*)d_in[11];
    const float* b_ih2 = (const float*)d_in[12];
    const float* b_hh2 = (const float*)d_in[13];
    const float* hw1   = (const float*)d_in[14];
    const float* hb1   = (const float*)d_in[15];
    const float* hw2   = (const float*)d_in[16];
    const float* hb2   = (const float*)d_in[17];
    float* out = (float*)d_out;

    // ws (53.6 MB, proven-safe):
    //   z    f16 [4][T][16][64]            16.78 MB
    //   xg1  f16 2x[4][TC][30][16][16]     15.73 MB
    //   xg2  f16 2x[4][TC][30][16][16]     15.73 MB
    //   h1c  f16 2x[4][TC][16][160]         5.24 MB
    //   h1s,h2s f32 [64][160]               2 x 40 KB
    char* p = (char*)d_ws;
    u32* z_ws  = (u32*)p;  p += (size_t)BB * TT * 32 * 4;
    u32* xg1_ws = (u32*)p; p += (size_t)2 * 4 * TC * 3840 * 4;
    u32* xg2_ws = (u32*)p; p += (size_t)2 * 4 * TC * 3840 * 4;
    u32* h1c_ws = (u32*)p; p += (size_t)2 * 4 * TC * 1280 * 4;
    float* h1s = (float*)p; p += (size_t)BB * HH * 4;
    float* h2s = (float*)p;

    conv_mfma_kernel<<<dim3(32, BB), 256, 0, stream>>>(
        x, mix_w, bn_g, bn_b, bn_m, bn_v, z_ws);

    for (int k = 0; k <= NC + 2; ++k) {
        pipe_stage<<<160, 512, 0, stream>>>(
            z_ws, xg1_ws, xg2_ws, h1c_ws, h1s, h2s,
            w_ih1, b_ih1, w_hh1, b_hh1,
            w_ih2, b_ih2, w_hh2, b_hh2, k);
    }

    head_kernel<<<BB, 256, 0, stream>>>(h2s, hw1, hb1, hw2, hb2, out);
}

// Round 10
// 1621.401 us; speedup vs baseline: 1.2047x; 1.2047x over previous
//
#include <hip/hip_runtime.h>
#include <cmath>

#define BB 64
#define TT 2048
#define FF 64
#define HH 160
#define G3 480
#define TC 128            // time-chunk length
#define NC (TT / TC)      // 16 chunks

#define L2E  1.44269504088896340736f
#define TL2E 2.88539008177792681472f

typedef unsigned int u32;
typedef _Float16 half8 __attribute__((ext_vector_type(8)));
typedef _Float16 half2v __attribute__((ext_vector_type(2)));
typedef float f32x4 __attribute__((ext_vector_type(4)));

__device__ __forceinline__ unsigned short f2h(float v) {
    _Float16 h = (_Float16)v;
    return __builtin_bit_cast(unsigned short, h);
}
__device__ __forceinline__ u32 packh2(float a, float b) {
    return (u32)f2h(a) | ((u32)f2h(b) << 16);
}
__device__ __forceinline__ u32 packhh(_Float16 a, _Float16 b) {
    return (u32)__builtin_bit_cast(unsigned short, a)
         | ((u32)__builtin_bit_cast(unsigned short, b) << 16);
}
// select f16 half by precomputed shift (0 or 16), then convert
__device__ __forceinline__ float h2sel(u32 p, u32 sh) {
    return (float)__builtin_bit_cast(half2v, p >> sh)[0];
}
// fast 1-ulp reciprocal / exp2 (avoid IEEE div + libm: no fast-math in harness)
__device__ __forceinline__ float frcp(float v) { return __builtin_amdgcn_rcpf(v); }
#if __has_builtin(__builtin_amdgcn_exp2f)
__device__ __forceinline__ float fexp2(float v) { return __builtin_amdgcn_exp2f(v); }
#else
__device__ __forceinline__ float fexp2(float v) { return __expf(v * 0.69314718055994530942f); }
#endif
__device__ __forceinline__ float gelu_exact(float v) {
    return 0.5f * v * (1.f + erff(v * 0.70710678118654752f));
}
// barrier that waits only on LDS ops (NOT vmcnt)
__device__ __forceinline__ void barrier_lgkm() {
    asm volatile("s_waitcnt lgkmcnt(0)\ns_barrier" ::: "memory");
}
// scaled variant: w -> f16(w * s). Folds log2(e) into gate weights so the
// scan's sigmoid/tanh use raw v_exp_f32 (exp2) with no pre-multiply.
__device__ __forceinline__ half8 load_wrow8s(const float* p, float s) {
    const float4* q = (const float4*)p;
    float4 a = q[0], b = q[1];
    half8 r;
    r[0] = (_Float16)(a.x * s); r[1] = (_Float16)(a.y * s);
    r[2] = (_Float16)(a.z * s); r[3] = (_Float16)(a.w * s);
    r[4] = (_Float16)(b.x * s); r[5] = (_Float16)(b.y * s);
    r[6] = (_Float16)(b.z * s); r[7] = (_Float16)(b.w * s);
    return r;
}
// split f32x8 into hi(f16) + lo(f16 of residual): hi+lo reproduces f32 to ~2^-22
__device__ __forceinline__ void split8(const float* v, half8& hi, half8& lo) {
    #pragma unroll
    for (int j = 0; j < 8; ++j) {
        _Float16 h = (_Float16)v[j];
        hi[j] = h;
        lo[j] = (_Float16)(v[j] - (float)h);
    }
}
#define MM16(A_, B_, C_) __builtin_amdgcn_mfma_f32_16x16x32_f16(A_, B_, C_, 0, 0, 0)

// ---------------------------------------------------------------------------
// K1: dilated conv + BN + exact GELU via MFMA (split-f16 for f32 accuracy).
// 64-t tiles (19 KB LDS -> 8 blocks/CU). x staged into LDS once (coalesced,
// pre-split hi/lo); z stored via LDS transpose tile (coalesced stores).
// ---------------------------------------------------------------------------
__global__ __launch_bounds__(256) void conv_mfma_kernel(
    const float* __restrict__ x, const float* __restrict__ mix_w,
    const float* __restrict__ bn_g, const float* __restrict__ bn_b,
    const float* __restrict__ bn_m, const float* __restrict__ bn_v,
    u32* __restrict__ z_out)
{
    __shared__ __align__(16) u32 xs[68 * 68];
    __shared__ __align__(8)  u32 zt[16 * 34];

    const int b   = blockIdx.y;
    const int t0  = blockIdx.x * 64;
    const int tid = threadIdx.x;
    const int wv = tid >> 6;
    const int lane = tid & 63;
    const int lane15 = lane & 15;
    const int quad = lane >> 4;

    {
        const float* xb = x + (size_t)b * TT * FF;
        for (int idx = tid; idx < 68 * 32; idx += 256) {
            const int row = idx >> 5;
            const int fp  = (idx & 31) * 2;
            const int t = t0 - 2 + row;
            float v0 = 0.f, v1 = 0.f;
            if (t >= 0 && t < TT) {
                float2 v = *(const float2*)(xb + (size_t)t * FF + fp);
                v0 = v.x; v1 = v.y;
            }
            _Float16 h0 = (_Float16)v0, h1 = (_Float16)v1;
            _Float16 l0 = (_Float16)(v0 - (float)h0);
            _Float16 l1 = (_Float16)(v1 - (float)h1);
            u32* rw = xs + row * 68;
            rw[(fp >> 1)]      = packhh(h0, h1);
            rw[32 + (fp >> 1)] = packhh(l0, l1);
        }
    }

    half8 Ahi[6], Alo[6];
    {
        const int fo = wv * 16 + lane15;
        const float* wrow = mix_w + fo * 192;
        #pragma unroll
        for (int s = 0; s < 6; ++s) {
            float wf[8];
            #pragma unroll
            for (int j = 0; j < 8; ++j) {
                int kap = s * 32 + quad * 8 + j;
                wf[j] = wrow[(kap & 63) * 3 + (kap >> 6)];
            }
            split8(wf, Ahi[s], Alo[s]);
        }
    }
    float sc[4], sh[4];
    #pragma unroll
    for (int r = 0; r < 4; ++r) {
        int f = wv * 16 + quad * 4 + r;
        float scl = bn_g[f] * rsqrtf(bn_v[f] + 1e-5f);
        sc[r] = scl; sh[r] = bn_b[f] - bn_m[f] * scl;
    }

    __syncthreads();

    u32* zrow = z_out + (size_t)(b >> 4) * TT * 512 + (b & 15) * 32;
    const int srow = tid >> 4;
    const int sc2  = tid & 15;

    for (int tt = 0; tt < 4; ++tt) {
        f32x4 C = {0.f, 0.f, 0.f, 0.f};
        #pragma unroll
        for (int s = 0; s < 6; ++s) {
            const int row = tt * 16 + lane15 + 2 * (s >> 1);
            const u32* rp = xs + row * 68 + (s & 1) * 16 + quad * 4;
            half8 Bhi = __builtin_bit_cast(half8, *(const uint4*)(rp));
            half8 Blo = __builtin_bit_cast(half8, *(const uint4*)(rp + 32));
            C = MM16(Ahi[s], Bhi, C);
            C = MM16(Ahi[s], Blo, C);
            C = MM16(Alo[s], Bhi, C);
        }
        float z0 = gelu_exact(fmaf(C[0], sc[0], sh[0]));
        float z1 = gelu_exact(fmaf(C[1], sc[1], sh[1]));
        float z2 = gelu_exact(fmaf(C[2], sc[2], sh[2]));
        float z3 = gelu_exact(fmaf(C[3], sc[3], sh[3]));
        const u32 q0 = packh2(z0, z1);
        const u32 q1 = packh2(z2, z3);
        __syncthreads();
        *(uint2*)(zt + lane15 * 34 + wv * 8 + quad * 2) = (uint2){q0, q1};
        __syncthreads();
        uint2 v = *(const uint2*)(zt + srow * 34 + sc2 * 2);
        *(uint2*)(zrow + (size_t)(t0 + tt * 16 + srow) * 512 + sc2 * 2) = v;
    }
}

// ---------------------------------------------------------------------------
// GEMM device body (MFMA): xg[t][tile][chain][n'/2] f16 pairs. 512 workers.
// Weights/biases pre-scaled by L2E (r,z: tiles 0..19) / TL2E (n: 20..29).
// ---------------------------------------------------------------------------
#define DECLAI(i) half8 A##i##_0, A##i##_1, A##i##_2, A##i##_3, A##i##_4;
#define GLOADA(i) { int tl = wv4 + (i); int rowc = tl < 30 ? tl * 16 + lane15 : 479; \
    float sA = tl < 20 ? L2E : TL2E;                                                 \
    const float* wp = W + (size_t)rowc * K + quad * 8;                               \
    A##i##_0 = load_wrow8s(wp, sA); A##i##_1 = load_wrow8s(wp + 32, sA);             \
    if (KT > 2) { A##i##_2 = load_wrow8s(wp + 64, sA);                               \
                  A##i##_3 = load_wrow8s(wp + 96, sA);                               \
                  A##i##_4 = load_wrow8s(wp + 128, sA); }                            \
    else { A##i##_2 = A##i##_0; A##i##_3 = A##i##_0; A##i##_4 = A##i##_0; } }
#define GMM(i, kt) C##i = MM16(A##i##_##kt, Bk##kt, C##i);

template<int K, int KT, int TG>
__device__ __forceinline__ void gemm_body(
    const unsigned short* __restrict__ in,
    size_t in_blk_stride, int t_off,
    const float* __restrict__ W, const float* __restrict__ b_ih,
    const float* __restrict__ b_hh, u32* __restrict__ xg,
    int gidx, int tid)
{
    if (tid >= 512) return;
    const int wv4 = (tid >> 6) * 4;
    const int lane = tid & 63;
    const int lane15 = lane & 15;
    const int quad = lane >> 4;
    const int blk = gidx >> 4;
    const int tbase = (gidx & 15) * TG;

    DECLAI(0) DECLAI(1) DECLAI(2) DECLAI(3)
    GLOADA(0) GLOADA(1) GLOADA(2) GLOADA(3)

    f32x4 BIAS0, BIAS1, BIAS2, BIAS3;
    #define GBIAS(i) { int tl = wv4 + (i); int rowb = tl < 30 ? tl * 16 + quad * 4 : 476; \
        float sB = tl < 20 ? L2E : TL2E;                                                  \
        float4 bi = *(const float4*)(b_ih + rowb);                                        \
        if (tl < 20) { float4 bh = *(const float4*)(b_hh + rowb);                         \
            bi.x += bh.x; bi.y += bh.y; bi.z += bh.z; bi.w += bh.w; }                     \
        BIAS##i[0] = bi.x * sB; BIAS##i[1] = bi.y * sB;                                   \
        BIAS##i[2] = bi.z * sB; BIAS##i[3] = bi.w * sB; }
    GBIAS(0) GBIAS(1) GBIAS(2) GBIAS(3)
    #undef GBIAS

    const unsigned short* inb = in + (size_t)blk * in_blk_stride;
    u32* xgb = xg + (size_t)blk * TC * 3840;

    for (int t = 0; t < TG; ++t) {
        const int tt = tbase + t;
        const unsigned short* ip =
            inb + ((size_t)(t_off + tt) * 16 + lane15) * K + quad * 8;
        half8 Bk0 = __builtin_bit_cast(half8, *(const uint4*)(ip));
        half8 Bk1 = __builtin_bit_cast(half8, *(const uint4*)(ip + 32));
        half8 Bk2 = Bk0, Bk3 = Bk0, Bk4 = Bk0;
        if (KT > 2) {
            Bk2 = __builtin_bit_cast(half8, *(const uint4*)(ip + 64));
            Bk3 = __builtin_bit_cast(half8, *(const uint4*)(ip + 96));
            Bk4 = __builtin_bit_cast(half8, *(const uint4*)(ip + 128));
        }
        f32x4 C0 = BIAS0, C1 = BIAS1, C2 = BIAS2, C3 = BIAS3;
        GMM(0, 0) GMM(1, 0) GMM(2, 0) GMM(3, 0)
        GMM(0, 1) GMM(1, 1) GMM(2, 1) GMM(3, 1)
        if (KT > 2) {
            GMM(0, 2) GMM(1, 2) GMM(2, 2) GMM(3, 2)
            GMM(0, 3) GMM(1, 3) GMM(2, 3) GMM(3, 3)
            GMM(0, 4) GMM(1, 4) GMM(2, 4) GMM(3, 4)
        }
        #define GSTORE(i) { int tl = wv4 + (i); if (tl < 30) {                      \
            u32 q0 = packh2(C##i[0], C##i[1]);                                      \
            u32 q1 = packh2(C##i[2], C##i[3]);                                      \
            *(uint2*)(xgb + (((size_t)tt * 30 + tl) * 16 + lane15) * 8 + quad * 2)  \
                = (uint2){q0, q1}; } }
        GSTORE(0) GSTORE(1) GSTORE(2) GSTORE(3)
        #undef GSTORE
    }
}

// ---------------------------------------------------------------------------
// Scan device body: 640 threads, 10 waves, 4 chains per block (R8 structure,
// R9's conflict-free LDS stride). Chains duplicated 4x across B-columns
// (col -> chain = col&3); dup = lane15>>2 picks 1 of the 4 C-rows, so each
// lane computes exactly ONE gate triple: 6 trans + ~25 VALU.
// LDS layout per parity: [chain:4][208 u16] (416 B stride, 104 dwords ==
// 8 mod 32 -> chain bank phases {0,8,16,24}; every bank exactly 2-way on
// each ds_read_b128 = conflict-free; R8's 336 B stride gave 3-way, 819K
// conflict cycles/dispatch).
// ---------------------------------------------------------------------------
#define DECLW(nm) half8 nm##0, nm##1, nm##2, nm##3, nm##4;
#define LOADWHS(nm, tb, S) { const float* wp = w_hh + (size_t)((tb) * 16 + lane15) * HH + quad * 8; \
    nm##0 = load_wrow8s(wp, S);       nm##1 = load_wrow8s(wp + 32, S);                              \
    nm##2 = load_wrow8s(wp + 64, S);  nm##3 = load_wrow8s(wp + 96, S);                              \
    nm##4 = load_wrow8s(wp + 128, S); }

template<bool WRITE_H>
__device__ __forceinline__ void scan_body(
    const u32* __restrict__ xg,          // f16 pairs [4][TC][30][16][8] u32
    const float* __restrict__ w_hh, const float* __restrict__ b_hh,
    float* __restrict__ h_state,         // [64][160] f32 carry
    u32* __restrict__ h_out32,           // [4][TC][16][160] f16 (if WRITE_H)
    int first, int blk, int sub, int tid, u32* h_lds32)
{
    const int wv = tid >> 6;
    const int lane = tid & 63;
    const int lane15 = lane & 15;
    const int quad = lane >> 4;
    const int ch   = lane15 & 3;      // chain within the block's 4
    const int dup  = lane15 >> 2;     // row select within C (0..3)
    const int ch0  = sub * 4;         // global chain base within blk
    const int row_g = wv * 16 + quad * 4 + dup;   // h row this lane owns
    const u32 shamt = (u32)(16 * (dup & 1));
    const bool d1 = (dup & 1) != 0;
    const bool d2 = (dup & 2) != 0;

    DECLW(Ar) DECLW(Az) DECLW(An)
    LOADWHS(Ar, wv, L2E) LOADWHS(Az, 10 + wv, L2E) LOADWHS(An, 20 + wv, TL2E)

    const float bh = b_hh[320 + row_g] * TL2E;   // n-gate hidden bias, this row

    float* hsp = h_state + (size_t)(blk * 16 + ch0 + ch) * HH + row_g;
    float ho = first ? 0.f : *hsp;

    // LDS u16 index: chain base 208 u16 (416 B) + row
    const int widx = ch * 208 + row_g;
    unsigned short* hw16 = (unsigned short*)h_lds32;
    unsigned short* HW0 = hw16 + widx;           // parity 0
    unsigned short* HW1 = hw16 + 832 + widx;     // parity 1 (416 u32)
    *HW0 = f2h(ho);

    // fragment read base (uint4 units): chain*26 + quad; slice stride 4
    const int vb = ch * 26 + quad;

    const u32* xgb = xg + (size_t)blk * TC * 3840;
    const int pr = quad * 2 + (dup >> 1);        // u32 pair slot within tile row
    const int xo_r = ((wv)      * 16 + ch0 + ch) * 8 + pr;
    const int xo_z = ((10 + wv) * 16 + ch0 + ch) * 8 + pr;
    const int xo_n = ((20 + wv) * 16 + ch0 + ch) * 8 + pr;

    // 4-deep prefetch ring: 3 u32 per step
    u32 xrP0 = xgb[0 * 3840 + xo_r], xzP0 = xgb[0 * 3840 + xo_z], xnP0 = xgb[0 * 3840 + xo_n];
    u32 xrP1 = xgb[1 * 3840 + xo_r], xzP1 = xgb[1 * 3840 + xo_z], xnP1 = xgb[1 * 3840 + xo_n];
    u32 xrP2 = xgb[2 * 3840 + xo_r], xzP2 = xgb[2 * 3840 + xo_z], xnP2 = xgb[2 * 3840 + xo_n];
    u32 xrP3 = xgb[3 * 3840 + xo_r], xzP3 = xgb[3 * 3840 + xo_z], xnP3 = xgb[3 * 3840 + xo_n];
    const u32* pf_r = xgb + 4 * 3840 + xo_r;
    const u32* pf_z = xgb + 4 * 3840 + xo_z;
    const u32* pf_n = xgb + 4 * 3840 + xo_n;

    // h1c: f16 at [blk][t][chain 16][row 160]
    unsigned short* hp = WRITE_H
            ? (unsigned short*)h_out32 + (size_t)blk * TC * 2560
              + (size_t)(ch0 + ch) * 160 + row_g
            : nullptr;
    __syncthreads();

    #define SCAN_STEP(RBOFF, HWP, XR, XZ, XN, PFO, HPO)                              \
    {                                                                                \
        const uint4* hb = (const uint4*)(h_lds32 + (RBOFF));                         \
        uint4 b0 = hb[vb];      uint4 b1 = hb[vb + 4];                               \
        uint4 b2 = hb[vb + 8];  uint4 b3 = hb[vb + 12];                              \
        uint4 b4 = hb[vb + 16];                                                      \
        float xrv = h2sel(XR, shamt);                                                \
        float xzv = h2sel(XZ, shamt);                                                \
        float xnv = h2sel(XN, shamt);                                                \
        f32x4 Cr = {xrv, xrv, xrv, xrv};                                             \
        f32x4 Cz = {xzv, xzv, xzv, xzv};                                             \
        f32x4 Cn = {bh, bh, bh, bh};                                                 \
        XR = pf_r[PFO]; XZ = pf_z[PFO]; XN = pf_n[PFO];                              \
        half8 B0 = __builtin_bit_cast(half8, b0);                                    \
        Cr = MM16(Ar0, B0, Cr); Cz = MM16(Az0, B0, Cz); Cn = MM16(An0, B0, Cn);      \
        half8 B1 = __builtin_bit_cast(half8, b1);                                    \
        Cr = MM16(Ar1, B1, Cr); Cz = MM16(Az1, B1, Cz); Cn = MM16(An1, B1, Cn);      \
        half8 B2 = __builtin_bit_cast(half8, b2);                                    \
        Cr = MM16(Ar2, B2, Cr); Cz = MM16(Az2, B2, Cz); Cn = MM16(An2, B2, Cn);      \
        half8 B3 = __builtin_bit_cast(half8, b3);                                    \
        Cr = MM16(Ar3, B3, Cr); Cz = MM16(Az3, B3, Cz); Cn = MM16(An3, B3, Cn);      \
        half8 B4 = __builtin_bit_cast(half8, b4);                                    \
        Cr = MM16(Ar4, B4, Cr); Cz = MM16(Az4, B4, Cz); Cn = MM16(An4, B4, Cn);      \
        {                                                                            \
            float ca = d1 ? Cr[1] : Cr[0];                                           \
            float cb = d1 ? Cr[3] : Cr[2];                                           \
            float crv = d2 ? cb : ca;                                                \
            ca = d1 ? Cz[1] : Cz[0];                                                 \
            cb = d1 ? Cz[3] : Cz[2];                                                 \
            float czv = d2 ? cb : ca;                                                \
            ca = d1 ? Cn[1] : Cn[0];                                                 \
            cb = d1 ? Cn[3] : Cn[2];                                                 \
            float cnv = d2 ? cb : ca;                                                \
            float r = frcp(1.f + fexp2(-crv));                                       \
            float u = frcp(1.f + fexp2(-czv));                                       \
            float e = fexp2(fmaf(r, cnv, xnv));                                      \
            float n = fmaf(-2.f, frcp(e + 1.f), 1.f);                                \
            ho = fmaf(u, ho - n, n);                                                 \
        }                                                                            \
        const unsigned short hv = f2h(ho);                                           \
        *(HWP) = hv;                                                                 \
        if (WRITE_H) { hp[HPO] = hv; }                                               \
        barrier_lgkm();                                                              \
    }

    for (int t4 = 0; t4 < TC; t4 += 4) {
        SCAN_STEP(0,   HW1, xrP0, xzP0, xnP0, 0 * 3840, 0 * 2560)
        SCAN_STEP(416, HW0, xrP1, xzP1, xnP1, 1 * 3840, 1 * 2560)
        SCAN_STEP(0,   HW1, xrP2, xzP2, xnP2, 2 * 3840, 2 * 2560)
        SCAN_STEP(416, HW0, xrP3, xzP3, xnP3, 3 * 3840, 3 * 2560)
        pf_r += 4 * 3840; pf_z += 4 * 3840; pf_n += 4 * 3840;
        if (WRITE_H) hp += 4 * 2560;
    }
    #undef SCAN_STEP

    *hsp = ho;
}

// ---------------------------------------------------------------------------
// K2: pipelined mega-dispatch. Stage k runs concurrently:
//   blocks 0..15   : scan1 chunk k-1   (blk = bx>>2, sub = bx&3)
//   blocks 16..31  : scan2 chunk k-3
//   blocks 32..95  : gemm1 chunk k     (64 blocks, TG=8)
//   blocks 96..159 : gemm2 chunk k-2   (64 blocks, TG=8)
// Producer->consumer edges cross dispatch boundaries; parity (chunk&1)
// double-buffers xg1/xg2/h1c against same-dispatch writers.
// Scan prefetch over-reads <=4 steps past its region; stays inside ws.
// ---------------------------------------------------------------------------
__global__ __launch_bounds__(640, 1) void pipe_stage(
    const u32* __restrict__ z,           // [4][TT][16][32] u32
    u32* __restrict__ xg1,               // 2 x [4][TC][3840] u32
    u32* __restrict__ xg2,
    u32* __restrict__ h1c,               // 2 x [4][TC][1280] u32
    float* __restrict__ h1s, float* __restrict__ h2s,
    const float* __restrict__ w_ih1, const float* __restrict__ b_ih1,
    const float* __restrict__ w_hh1, const float* __restrict__ b_hh1,
    const float* __restrict__ w_ih2, const float* __restrict__ b_ih2,
    const float* __restrict__ w_hh2, const float* __restrict__ b_hh2,
    int k)
{
    __shared__ __align__(16) u32 h_lds32[2 * 416];
    const int bx = blockIdx.x;
    const int tid = threadIdx.x;
    const size_t XGCH = (size_t)4 * TC * 3840;   // u32 per parity buffer
    const size_t H1CH = (size_t)4 * TC * 1280;

    if (bx < 16) {
        const int c = k - 1;
        if (c < 0 || c >= NC) return;
        scan_body<true>(xg1 + (c & 1) * XGCH, w_hh1, b_hh1, h1s,
                        h1c + (c & 1) * H1CH, c == 0, bx >> 2, bx & 3, tid, h_lds32);
    } else if (bx < 32) {
        const int c = k - 3;
        if (c < 0 || c >= NC) return;
        scan_body<false>(xg2 + (c & 1) * XGCH, w_hh2, b_hh2, h2s,
                         nullptr, c == 0, (bx - 16) >> 2, (bx - 16) & 3, tid, h_lds32);
    } else if (bx < 96) {
        const int c = k;
        if (c >= NC) return;
        gemm_body<64, 2, 8>((const unsigned short*)z, (size_t)TT * 1024, c * TC,
                            w_ih1, b_ih1, b_hh1, xg1 + (c & 1) * XGCH, bx - 32, tid);
    } else {
        const int c = k - 2;
        if (c < 0 || c >= NC) return;
        gemm_body<160, 5, 8>((const unsigned short*)(h1c + (c & 1) * H1CH),
                             (size_t)TC * 2560, 0,
                             w_ih2, b_ih2, b_hh2, xg2 + (c & 1) * XGCH, bx - 96, tid);
    }
}

// ---------------------------------------------------------------------------
// K3: MLP head from h2 final state.
// ---------------------------------------------------------------------------
__global__ __launch_bounds__(256) void head_kernel(
    const float* __restrict__ h_state,
    const float* __restrict__ hw1, const float* __restrict__ hb1,
    const float* __restrict__ hw2, const float* __restrict__ hb2,
    float* __restrict__ out)
{
    const int b = blockIdx.x;
    const int tid = threadIdx.x;
    __shared__ float hf[HH];
    __shared__ float q[80];
    if (tid < HH) hf[tid] = h_state[b * HH + tid];
    __syncthreads();
    if (tid < 80) {
        float a = hb1[tid];
        const float* wr = hw1 + (size_t)tid * HH;
        #pragma unroll 8
        for (int i = 0; i < HH; ++i) a = fmaf(wr[i], hf[i], a);
        q[tid] = gelu_exact(a);
    }
    __syncthreads();
    if (tid < 2) {
        float o = hb2[tid];
        const float* wr = hw2 + tid * 80;
        #pragma unroll 8
        for (int j = 0; j < 80; ++j) o = fmaf(wr[j], q[j], o);
        out[b * 2 + tid] = o;
    }
}

// ---------------------------------------------------------------------------
extern "C" void kernel_launch(void* const* d_in, const int* in_sizes, int n_in,
                              void* d_out, int out_size, void* d_ws, size_t ws_size,
                              hipStream_t stream)
{
    const float* x     = (const float*)d_in[0];
    const float* mix_w = (const float*)d_in[1];
    const float* bn_g  = (const float*)d_in[2];
    const float* bn_b  = (const float*)d_in[3];
    const float* bn_m  = (const float*)d_in[4];
    const float* bn_v  = (const float*)d_in[5];
    const float* w_ih1 = (const float*)d_in[6];
    const float* w_hh1 = (const float*)d_in[7];
    const float* b_ih1 = (const float*)d_in[8];
    const float* b_hh1 = (const float*)d_in[9];
    const float* w_ih2 = (const float*)d_in[10];
    const float* w_hh2 = (const float*)d_in[11];
    const float* b_ih2 = (const float*)d_in[12];
    const float* b_hh2 = (const float*)d_in[13];
    const float* hw1   = (const float*)d_in[14];
    const float* hb1   = (const float*)d_in[15];
    const float* hw2   = (const float*)d_in[16];
    const float* hb2   = (const float*)d_in[17];
    float* out = (float*)d_out;

    // ws (53.6 MB, proven-safe):
    //   z    f16 [4][T][16][64]            16.78 MB
    //   xg1  f16 2x[4][TC][30][16][16]     15.73 MB
    //   xg2  f16 2x[4][TC][30][16][16]     15.73 MB
    //   h1c  f16 2x[4][TC][16][160]         5.24 MB
    //   h1s,h2s f32 [64][160]               2 x 40 KB
    char* p = (char*)d_ws;
    u32* z_ws  = (u32*)p;  p += (size_t)BB * TT * 32 * 4;
    u32* xg1_ws = (u32*)p; p += (size_t)2 * 4 * TC * 3840 * 4;
    u32* xg2_ws = (u32*)p; p += (size_t)2 * 4 * TC * 3840 * 4;
    u32* h1c_ws = (u32*)p; p += (size_t)2 * 4 * TC * 1280 * 4;
    float* h1s = (float*)p; p += (size_t)BB * HH * 4;
    float* h2s = (float*)p;

    conv_mfma_kernel<<<dim3(32, BB), 256, 0, stream>>>(
        x, mix_w, bn_g, bn_b, bn_m, bn_v, z_ws);

    for (int k = 0; k <= NC + 2; ++k) {
        pipe_stage<<<160, 640, 0, stream>>>(
            z_ws, xg1_ws, xg2_ws, h1c_ws, h1s, h2s,
            w_ih1, b_ih1, w_hh1, b_hh1,
            w_ih2, b_ih2, w_hh2, b_hh2, k);
    }

    head_kernel<<<BB, 256, 0, stream>>>(h2s, hw1, hb1, hw2, hb2, out);
}